// Round 13
// baseline (25.177 us; speedup 1.0000x reference)
//
#include <hip/hip_runtime.h>
#include <math.h>

#define FN 50
#define CARD 10000
#define NP 1225          // F*(F-1)/2
#define NPAD 1232        // pair-table entries (16-pad)
#define NT32 39          // ceil(NP/32) 32-pair tiles
#define FSTRIDE 72       // halves per factor row (144 B)

typedef _Float16 half8 __attribute__((ext_vector_type(8)));
typedef __fp16 half2t __attribute__((ext_vector_type(2)));
typedef __fp16 half4t __attribute__((ext_vector_type(4)));
typedef float floatx4 __attribute__((ext_vector_type(4)));
typedef float floatx16 __attribute__((ext_vector_type(16)));

static __device__ __forceinline__ half2t h2max0(half2t v) {
  half2t r;
  r[0] = v[0] > (__fp16)0 ? v[0] : (__fp16)0;
  r[1] = v[1] > (__fp16)0 ? v[1] : (__fp16)0;
  return r;
}
static __device__ __forceinline__ float hdot2(half2t a, half2t b, float c) {
#if __has_builtin(__builtin_amdgcn_fdot2)
  return __builtin_amdgcn_fdot2(a, b, c, false);
#else
  return c + (float)a[0]*(float)b[0] + (float)a[1]*(float)b[1];
#endif
}

__global__ __launch_bounds__(256, 4)
void afm_kernel(const int* __restrict__ inp,
                const float* __restrict__ emb,
                const float* __restrict__ wlin,
                const float* __restrict__ blin,
                const float* __restrict__ W1,
                const float* __restrict__ b1,
                const float* __restrict__ W2,
                const float* __restrict__ b2,
                float* __restrict__ out)
{
  __shared__ __align__(16) _Float16 s_fac[FN][FSTRIDE];   // 7200 B
  __shared__ __align__(16) _Float16 s_w1[512 * 8];        // 8192 B, 32x32 frag layout
  __shared__ __align__(16) unsigned s_pij[NPAD];          // 4928 B
  __shared__ float s_wl[FN];
  __shared__ float s_red[16];

  const int tid  = threadIdx.x;
  const int b    = blockIdx.x;
  const int lane = tid & 63;
  const int wave = tid >> 6;
  const int n32  = lane & 31;   // pair column (B-frag n / D col)
  const int hi   = lane >> 5;   // k-half / row-offset group

  // ---- phase 0a: pair table (closed form + fixup) ----
  for (int p = tid; p < NPAD; p += 256) {
    int pp = p < NP ? p : NP - 1;
    int i = (int)((99.0f - sqrtf(9801.0f - 8.0f * (float)pp)) * 0.5f);
    if (i < 0) i = 0;
    while ((i + 1) * (98 - i) / 2 <= pp) ++i;
    while (i > 0 && i * (99 - i) / 2 > pp) --i;
    int j = pp - i * (99 - i) / 2 + i + 1;
    s_pij[p] = (unsigned)(i * (FSTRIDE * 2)) | ((unsigned)(j * (FSTRIDE * 2)) << 16);
  }

  // ---- phase 0b: factor gather f32 -> f16 LDS (packed 8B writes) ----
  const int* inprow = inp + b * FN;
  for (int idx = tid; idx < FN * 16; idx += 256) {
    int f = idx >> 4, q = idx & 15;
    int flat = inprow[f] + f * CARD;
    floatx4 v = ((const floatx4*)emb)[(long)flat * 16 + q];
    half2t lo = __builtin_amdgcn_cvt_pkrtz(v[0], v[1]);
    half2t hi2 = __builtin_amdgcn_cvt_pkrtz(v[2], v[3]);
    half4t pk = {lo[0], lo[1], hi2[0], hi2[1]};
    *(half4t*)&s_fac[f][q * 4] = pk;
  }
  if (tid < FN) {
    int flat = inprow[tid] + tid * CARD;
    s_wl[tid] = wlin[flat];
  }

  // ---- phase 0c: stage W1 (as W1^T) in 32x32x16 A-frag layout ----
  // chunk ch = mt*256 + ks*64 + ln: halves j=0..7 of A[a = mt*32+(ln&31)][k = ks*16+(ln>>5)*8+j]
  for (int ch = tid; ch < 512; ch += 256) {
    int mt = ch >> 8, ks = (ch >> 6) & 3, ln = ch & 63;
    int a = mt * 32 + (ln & 31);
    int kb = ks * 16 + (ln >> 5) * 8;
    __fp16 tmp[8];
#pragma unroll
    for (int j = 0; j < 4; ++j) {
      half2t hw = __builtin_amdgcn_cvt_pkrtz(W1[(kb + 2 * j) * 64 + a],
                                             W1[(kb + 2 * j + 1) * 64 + a]);
      tmp[2 * j] = hw[0]; tmp[2 * j + 1] = hw[1];
    }
    *(half8*)&s_w1[ch * 8] = *(const half8*)tmp;
  }

  // per-lane b1/W2 slices for 32x32 D-layout: row = (reg&3) + 8*(reg>>2) + 4*hi
  half2t b1h[2][4][2], w2h[2][4][2];
#pragma unroll
  for (int mt = 0; mt < 2; ++mt)
#pragma unroll
    for (int q = 0; q < 4; ++q) {
      floatx4 bv = *(const floatx4*)&b1[mt * 32 + q * 8 + 4 * hi];
      floatx4 wv = *(const floatx4*)&W2[mt * 32 + q * 8 + 4 * hi];
      b1h[mt][q][0] = __builtin_amdgcn_cvt_pkrtz(bv[0], bv[1]);
      b1h[mt][q][1] = __builtin_amdgcn_cvt_pkrtz(bv[2], bv[3]);
      w2h[mt][q][0] = __builtin_amdgcn_cvt_pkrtz(wv[0], wv[1]);
      w2h[mt][q][1] = __builtin_amdgcn_cvt_pkrtz(wv[2], wv[3]);
    }
  const half2t one2 = {(__fp16)1, (__fp16)1};

  __syncthreads();

  // ---- phase 1: 32-pair tiles via mfma_f32_32x32x16_f16, fused softmax ----
#define LDW1(mt, ks) (*(const half8*)&s_w1[(((mt) * 4 + (ks)) * 64 + lane) * 8])
  const char* fbase = (const char*)&s_fac[0][0];
  const int hib = hi * 16;                     // byte offset of this lane's k-half (8 halves)
  float se = 0.f, spe = 0.f;
  {
    int t = wave;
    int p = t * 32 + n32;
    unsigned po = s_pij[p < NPAD ? p : NPAD - 1];
    int pn1 = (t + 4) * 32 + n32; if (pn1 > NPAD - 1) pn1 = NPAD - 1;
    unsigned po_nx = s_pij[pn1];               // 1 tile ahead

    while (true) {
      int pn2 = (t + 8) * 32 + n32; if (pn2 > NPAD - 1) pn2 = NPAD - 1;
      unsigned po_n2 = s_pij[pn2];             // 2 ahead

      int offi = (int)(po & 0xffffu) + hib;
      int offj = (int)(po >> 16) + hib;
      half8 pr[4];
#pragma unroll
      for (int ks = 0; ks < 4; ++ks) {
        half8 fi = *(const half8*)(fbase + offi + ks * 32);
        half8 fj = *(const half8*)(fbase + offj + ks * 32);
        pr[ks] = fi * fj;                      // B-frag: inter[k-slice][pair]
      }

      float lg = 0.f;
#pragma unroll
      for (int mt = 0; mt < 2; ++mt) {
        floatx16 acc = {0.f};
#pragma unroll
        for (int ks = 0; ks < 4; ++ks)
          acc = __builtin_amdgcn_mfma_f32_32x32x16_f16(LDW1(mt, ks), pr[ks], acc, 0, 0, 0);
        // epilogue: rows (reg&3)+8*(reg>>2)+4*hi ; bias+relu+W2-dot, f16 packed
#pragma unroll
        for (int q = 0; q < 4; ++q) {
          half2t h0 = __builtin_amdgcn_cvt_pkrtz(acc[q * 4 + 0], acc[q * 4 + 1]);
          half2t h1 = __builtin_amdgcn_cvt_pkrtz(acc[q * 4 + 2], acc[q * 4 + 3]);
          h0 = h2max0(h0 + b1h[mt][q][0]);
          h1 = h2max0(h1 + b1h[mt][q][1]);
          lg = hdot2(h0, w2h[mt][q][0], lg);
          lg = hdot2(h1, w2h[mt][q][1], lg);
        }
      }
      // pooled partial: this lane's 32 k-values of inter
      float pool = 0.f;
#pragma unroll
      for (int ks = 0; ks < 4; ++ks) {
        const half2t* pp2 = (const half2t*)&pr[ks];
#pragma unroll
        for (int q = 0; q < 4; ++q) pool = hdot2(pp2[q], one2, pool);
      }
      // combine the two k-halves / row-halves (lane ^ 32)
      lg   += __shfl_xor(lg, 32, 64);
      pool += __shfl_xor(pool, 32, 64);
      float e = __expf(lg);
      if (hi == 0 && p < NP) { se += e; spe += e * pool; }

      t += 4;
      if (t >= NT32) break;
      p = t * 32 + n32;
      po = po_nx; po_nx = po_n2;
    }
  }
#undef LDW1

  // reduce se/spe across the wave (lanes >=32 hold zeros)
#pragma unroll
  for (int o = 1; o <= 32; o <<= 1) {
    se  += __shfl_xor(se, o, 64);
    spe += __shfl_xor(spe, o, 64);
  }
  if (lane == 0) { s_red[wave] = se; s_red[8 + wave] = spe; }
  __syncthreads();
  if (tid == 0) {
    float line = blin[0];
#pragma unroll
    for (int f = 0; f < FN; ++f) line += s_wl[f];
    float SE  = s_red[0] + s_red[1] + s_red[2]  + s_red[3];
    float SPE = s_red[8] + s_red[9] + s_red[10] + s_red[11];
    out[b] = line + SPE / SE;
  }
}

extern "C" void kernel_launch(void* const* d_in, const int* in_sizes, int n_in,
                              void* d_out, int out_size, void* d_ws, size_t ws_size,
                              hipStream_t stream) {
  const int*   inp  = (const int*)d_in[0];
  const float* emb  = (const float*)d_in[1];
  const float* wlin = (const float*)d_in[2];
  const float* blin = (const float*)d_in[3];
  const float* W1   = (const float*)d_in[4];
  const float* b1   = (const float*)d_in[5];
  const float* W2   = (const float*)d_in[6];
  const float* b2   = (const float*)d_in[7];
  float* outp = (float*)d_out;
  const int B = in_sizes[0] / FN;
  afm_kernel<<<B, 256, 0, stream>>>(inp, emb, wlin, blin, W1, b1, W2, b2, outp);
}